// Round 6
// baseline (1185.052 us; speedup 1.0000x reference)
//
#include <hip/hip_runtime.h>
#include <cstdint>
#include <cstddef>

#define INDIM 512
#define HIDD  256
#define OUTD  32

typedef __attribute__((ext_vector_type(4))) float f32x4;
typedef __attribute__((ext_vector_type(8))) short bf16x8;

// ---- bf16 <-> f32 helpers ----
static inline __device__ float b2f(unsigned short u) {
  union { float f; unsigned int i; } v; v.i = ((unsigned int)u) << 16; return v.f;
}
static inline __device__ unsigned short f2b(float f) {
  union { float f; unsigned int i; } v; v.f = f;
  unsigned int x = v.i;
  x += 0x7fffu + ((x >> 16) & 1u);   // round-to-nearest-even
  return (unsigned short)(x >> 16);
}

// async global->LDS, 16B per lane. LDS dest = wave-uniform base + lane*16.
static __device__ __forceinline__ void gld16(const unsigned short* g, unsigned short* l) {
  __builtin_amdgcn_global_load_lds(
      (const __attribute__((address_space(1))) void*)g,
      (__attribute__((address_space(3))) void*)l, 16, 0, 0);
}

// ---- runtime dtype probe ----
// flags[0] = 1 if float tensors are bf16 on device, 0 if f32
// flags[1] = 1 if edge_index is int64 on device, 0 if int32
__global__ __launch_bounds__(256) void probe_kernel(
    const unsigned int* __restrict__ feat, const unsigned int* __restrict__ eidx,
    int* __restrict__ flags)
{
  int t = threadIdx.x;
  __shared__ int cnt, oddnz;
  if (t == 0) { cnt = 0; oddnz = 0; }
  __syncthreads();
  unsigned int w = feat[t];
  unsigned short lo = (unsigned short)(w & 0xFFFFu);
  int e = (lo >> 7) & 0xFF;
  int plausible = ((lo & 0x7FFF) == 0) || (e >= 0x60 && e <= 0x9F);
  atomicAdd(&cnt, plausible);
  if (t & 1) { if (eidx[t] != 0u) atomicAdd(&oddnz, 1); }
  __syncthreads();
  if (t == 0) { flags[0] = (cnt >= 192) ? 1 : 0; flags[1] = (oddnz == 0) ? 1 : 0; }
}

// ---- edge_index -> int32 src/dst + degree histogram ----
__global__ __launch_bounds__(256) void convert_idx(
    const unsigned int* __restrict__ eidx, int* __restrict__ srcN, int* __restrict__ dstN,
    int* __restrict__ deg, int E, const int* __restrict__ flags)
{
  int ee = blockIdx.x * 256 + threadIdx.x;
  if (ee >= E) return;
  int s, d;
  if (flags[1]) {
    s = (int)eidx[2 * (size_t)ee];
    d = (int)eidx[2 * ((size_t)E + ee)];
  } else {
    s = (int)eidx[ee];
    d = (int)eidx[(size_t)E + ee];
  }
  srcN[ee] = s;
  dstN[ee] = d;
  atomicAdd(&deg[d], 1);
}

static inline __device__ float ldadapt(const void* p, size_t i, int isbf) {
  return isbf ? b2f(((const unsigned short*)p)[i]) : ((const float*)p)[i];
}

// ---- features -> bf16 (or pass-through copy) ----
__global__ __launch_bounds__(256) void convb_kernel(
    const void* __restrict__ in, unsigned short* __restrict__ outb, size_t n4,
    const int* __restrict__ flags)
{
  const int fb = flags[0];
  size_t i = (size_t)blockIdx.x * 256 + threadIdx.x;
  size_t stride = (size_t)gridDim.x * 256;
  if (fb) {
    const ushort4* ip = (const ushort4*)in;
    ushort4* op = (ushort4*)outb;
    for (; i < n4; i += stride) op[i] = ip[i];
  } else {
    const float4* ip = (const float4*)in;
    ushort4* op = (ushort4*)outb;
    for (; i < n4; i += stride) {
      float4 v = ip[i];
      ushort4 o; o.x = f2b(v.x); o.y = f2b(v.y); o.z = f2b(v.z); o.w = f2b(v.w);
      op[i] = o;
    }
  }
}

// ---- weight prep: W1b [512][256] bf16, W1tb [256][512] bf16, W2f f32, att f32 ----
__global__ __launch_bounds__(256) void prep_weights(
    const void* __restrict__ W1, const void* __restrict__ W2,
    const void* __restrict__ aS, const void* __restrict__ aD,
    unsigned short* __restrict__ W1b, unsigned short* __restrict__ W1tb,
    float* __restrict__ W2f,
    float* __restrict__ atS, float* __restrict__ atD,
    const int* __restrict__ flags)
{
  const int fb = flags[0];
  int i = blockIdx.x * 256 + threadIdx.x;
  if (i < INDIM * HIDD) {               // W1: [512][256]
    int r = i >> 8, c = i & 255;
    float w0 = ldadapt(W1, i, fb);
    unsigned short wb = f2b(w0);
    W1b[i] = wb;                        // Bt for h4: [512 rows][256 k]
    W1tb[c * INDIM + r] = wb;           // Bt for xp1: [256 rows][512 k]
  }
  if (i < HIDD * OUTD) W2f[i] = ldadapt(W2, i, fb);
  if (i < HIDD) { atS[i] = ldadapt(aS, i, fb); atD[i] = ldadapt(aD, i, fb); }
}

// =====================================================================
// m97-structure MFMA NT GEMM: C[M][Nn] = A @ Bt^T, bf16 in.
// =====================================================================
template<int OUTMODE>
__global__ __launch_bounds__(256) void gemm_nt2(
    const unsigned short* __restrict__ A, const unsigned short* __restrict__ Bt,
    unsigned short* __restrict__ Cb, void* __restrict__ Out, size_t outOff,
    const int* __restrict__ flags, int M, int Nn, int K)
{
  __shared__ unsigned short Als[128 * 64];
  __shared__ unsigned short Bls[128 * 64];
  const int tid = threadIdx.x, lane = tid & 63, wid = tid >> 6;
  const int wr = wid >> 1, wc = wid & 1;
  const int rowBase = blockIdx.y * 128, colBase = blockIdx.x * 128;
  const int fb = flags[0];

  const int srow = (lane >> 3), sg = lane & 7;

  f32x4 acc[4][4] = {};

  for (int kt = 0; kt < K; kt += 64) {
#pragma unroll
    for (int i = 0; i < 4; ++i) {
      int row = wid * 32 + i * 8 + srow;
      gld16(A + (size_t)(rowBase + row) * K + kt + sg * 8, Als + (wid * 4 + i) * 512);
      gld16(Bt + (size_t)(colBase + row) * K + kt + sg * 8, Bls + (wid * 4 + i) * 512);
    }
    __syncthreads();

    bf16x8 af[4], bfr[4];
#pragma unroll
    for (int ks = 0; ks < 2; ++ks) {
      int g = ks * 4 + (lane >> 4);
#pragma unroll
      for (int mi = 0; mi < 4; ++mi) {
        int row = wr * 64 + mi * 16 + (lane & 15);
        af[mi] = *(const bf16x8*)(Als + row * 64 + g * 8);
      }
#pragma unroll
      for (int ni = 0; ni < 4; ++ni) {
        int row = wc * 64 + ni * 16 + (lane & 15);
        bfr[ni] = *(const bf16x8*)(Bls + row * 64 + g * 8);
      }
#pragma unroll
      for (int mi = 0; mi < 4; ++mi)
#pragma unroll
        for (int ni = 0; ni < 4; ++ni)
          acc[mi][ni] = __builtin_amdgcn_mfma_f32_16x16x32_bf16(af[mi], bfr[ni], acc[mi][ni], 0, 0, 0);
    }
    __syncthreads();
  }

  // C/D: col = lane&15, row = (lane>>4)*4 + reg
#pragma unroll
  for (int mi = 0; mi < 4; ++mi) {
    int r0 = rowBase + wr * 64 + mi * 16 + (lane >> 4) * 4;
#pragma unroll
    for (int ni = 0; ni < 4; ++ni) {
      int c = colBase + wc * 64 + ni * 16 + (lane & 15);
#pragma unroll
      for (int v = 0; v < 4; ++v) {
        int r = r0 + v;
        if (r < M) {
          size_t idx = (size_t)r * Nn + c;
          if (OUTMODE == 0) Cb[idx] = f2b(acc[mi][ni][v]);
          else {
            if (fb) ((unsigned short*)Out)[outOff + idx] = f2b(acc[mi][ni][v]);
            else    ((float*)Out)[outOff + idx] = acc[mi][ni][v];
          }
        }
      }
    }
  }
}

// ---- a_src / a_dst: one wave per node, dot(xp1_row, att); P is bf16 ----
__global__ __launch_bounds__(256) void rowdots(
    const unsigned short* __restrict__ P, const float* __restrict__ atS,
    const float* __restrict__ atD,
    float* __restrict__ asrc, float* __restrict__ adst, int N)
{
  int wave = threadIdx.x >> 6, lane = threadIdx.x & 63;
  int node = blockIdx.x * 4 + wave;
  if (node >= N) return;
  ushort4 u = *(const ushort4*)(P + (size_t)node * HIDD + lane * 4);
  float4 v = make_float4(b2f(u.x), b2f(u.y), b2f(u.z), b2f(u.w));
  float4 s = *(const float4*)(atS + lane * 4);
  float4 d = *(const float4*)(atD + lane * 4);
  float s1 = v.x * s.x + v.y * s.y + v.z * s.z + v.w * s.w;
  float s2 = v.x * d.x + v.y * d.y + v.z * d.z + v.w * d.w;
#pragma unroll
  for (int off = 32; off; off >>= 1) {
    s1 += __shfl_down(s1, off);
    s2 += __shfl_down(s2, off);
  }
  if (lane == 0) { asrc[node] = s1; adst[node] = s2; }
}

// ---- multi-block exclusive scan ----
__global__ __launch_bounds__(256) void scan_p1(const int* __restrict__ deg,
                                               int* __restrict__ bsum, int N)
{
  int b = blockIdx.x, t = threadIdx.x;
  int i0 = b * 1024 + t * 4;
  int s = 0;
#pragma unroll
  for (int j = 0; j < 4; ++j) { int i = i0 + j; if (i < N) s += deg[i]; }
  __shared__ int red[256];
  red[t] = s;
  __syncthreads();
  for (int o = 128; o; o >>= 1) {
    if (t < o) red[t] += red[t + o];
    __syncthreads();
  }
  if (t == 0) bsum[b] = red[0];
}

__global__ __launch_bounds__(256) void scan_p2(int* __restrict__ bsum, int nb)
{
  __shared__ int sh[256];
  int t = threadIdx.x;
  int v = (t < nb) ? bsum[t] : 0;
  sh[t] = v;
  __syncthreads();
  for (int o = 1; o < 256; o <<= 1) {
    int u = (t >= o) ? sh[t - o] : 0;
    __syncthreads();
    sh[t] += u;
    __syncthreads();
  }
  if (t < nb) bsum[t] = sh[t] - v;   // exclusive
}

__global__ __launch_bounds__(256) void scan_p3(const int* __restrict__ deg,
                                               const int* __restrict__ bsum,
                                               int* __restrict__ offs, int* __restrict__ cur,
                                               int N, int nb)
{
  int b = blockIdx.x, t = threadIdx.x;
  int i0 = b * 1024 + t * 4;
  int v[4]; int s = 0;
#pragma unroll
  for (int j = 0; j < 4; ++j) { int i = i0 + j; v[j] = (i < N) ? deg[i] : 0; s += v[j]; }
  __shared__ int sh[256];
  sh[t] = s;
  __syncthreads();
  for (int o = 1; o < 256; o <<= 1) {
    int u = (t >= o) ? sh[t - o] : 0;
    __syncthreads();
    sh[t] += u;
    __syncthreads();
  }
  int run = bsum[b] + sh[t] - s;
#pragma unroll
  for (int j = 0; j < 4; ++j) {
    int i = i0 + j;
    if (i < N) { offs[i] = run; cur[i] = run; }
    run += v[j];
  }
  if (b == nb - 1 && t == 255) offs[N] = run;   // total = E
}

// ---- fused fill+coef: CSR-ordered srcP/coefP + denominator atomics ----
__global__ __launch_bounds__(256) void fillcoef_kernel(
    const int* __restrict__ srcN, const int* __restrict__ dstN,
    const float* __restrict__ asrc, const float* __restrict__ adst,
    int* __restrict__ cur, int* __restrict__ srcP, float* __restrict__ coefP,
    float* __restrict__ srec, int E)
{
  int e = blockIdx.x * 256 + threadIdx.x;
  if (e >= E) return;
  int s = srcN[e], d = dstN[e];
  float x = asrc[s] + adst[d];
  float al = 1.f / (1.f + __expf(-x));    // sigmoid in (0,1): segment-max unneeded
  float t = __expf(al);
  int pos = atomicAdd(&cur[d], 1);
  srcP[pos] = s;
  coefP[pos] = t;
  atomicAdd(&srec[d], t);
}

// ---- agg layer 1: wave per node, 4 ch/lane, 8 gathers in flight, /denom + ELU ----
__global__ __launch_bounds__(256) void agg_elu2(
    const unsigned short* __restrict__ xp, const float* __restrict__ coefP,
    const int* __restrict__ srcP, const float* __restrict__ srec,
    const int* __restrict__ offs, unsigned short* __restrict__ hout, int N)
{
  __shared__ int   sS[4][64];
  __shared__ float sW[4][64];
  int wid = threadIdx.x >> 6, lane = threadIdx.x & 63;
  int node = blockIdx.x * 4 + wid;
  if (node >= N) return;
  int s0 = offs[node], s1 = offs[node + 1];
  float a0 = 0.f, a1 = 0.f, a2 = 0.f, a3 = 0.f;
  for (int base = s0; base < s1; base += 64) {
    int cnt = s1 - base; if (cnt > 64) cnt = 64;
    if (lane < cnt) {
      sS[wid][lane] = srcP[base + lane];
      sW[wid][lane] = coefP[base + lane];
    }
    asm volatile("s_waitcnt lgkmcnt(0)" ::: "memory");   // wave-local LDS RAW fence
    int j = 0;
    for (; j + 8 <= cnt; j += 8) {
      ushort4 u[8];
#pragma unroll
      for (int q = 0; q < 8; ++q)
        u[q] = *(const ushort4*)(xp + (size_t)sS[wid][j + q] * HIDD + lane * 4);
#pragma unroll
      for (int q = 0; q < 8; ++q) {
        float wv = sW[wid][j + q];
        a0 += wv * b2f(u[q].x); a1 += wv * b2f(u[q].y);
        a2 += wv * b2f(u[q].z); a3 += wv * b2f(u[q].w);
      }
    }
    for (; j < cnt; ++j) {
      int   sv = sS[wid][j];
      float wv = sW[wid][j];
      ushort4 u = *(const ushort4*)(xp + (size_t)sv * HIDD + lane * 4);
      a0 += wv * b2f(u.x); a1 += wv * b2f(u.y); a2 += wv * b2f(u.z); a3 += wv * b2f(u.w);
    }
  }
  float inv = 1.f / (srec[node] + 1e-16f);
  float r0 = a0 * inv, r1 = a1 * inv, r2 = a2 * inv, r3 = a3 * inv;
  r0 = r0 > 0.f ? r0 : expm1f(r0);
  r1 = r1 > 0.f ? r1 : expm1f(r1);
  r2 = r2 > 0.f ? r2 : expm1f(r2);
  r3 = r3 > 0.f ? r3 : expm1f(r3);
  ushort4 o; o.x = f2b(r0); o.y = f2b(r1); o.z = f2b(r2); o.w = f2b(r3);
  *(ushort4*)(hout + (size_t)node * HIDD + lane * 4) = o;
}

// ---- h2 = h1 @ W2 ([N,256]x[256,32]) -> adaptive out + bf16 copy ----
__global__ __launch_bounds__(256) void gemm_h2(
    const unsigned short* __restrict__ H1, const float* __restrict__ W2f,
    void* __restrict__ Out, unsigned short* __restrict__ h2b,
    const int* __restrict__ flags, int M)
{
  const int fb = flags[0];
  __shared__ float Bs[HIDD][33];
  __shared__ float As[8][HIDD];
  int tid = threadIdx.x;
  int tx = tid & 31, ty = tid >> 5;
  int row0 = blockIdx.x * 8;
#pragma unroll
  for (int j = 0; j < 32; ++j) {
    int idx = tid + 256 * j;
    Bs[idx >> 5][idx & 31] = W2f[idx];
  }
#pragma unroll
  for (int j = 0; j < 8; ++j) {
    int idx = tid + 256 * j;
    int r = idx >> 8, k = idx & 255;
    As[r][k] = (row0 + r < M) ? b2f(H1[(size_t)(row0 + r) * HIDD + k]) : 0.f;
  }
  __syncthreads();
  float acc = 0.f;
#pragma unroll 8
  for (int k = 0; k < HIDD; ++k) acc += As[ty][k] * Bs[k][tx];
  int row = row0 + ty;
  if (row < M) {
    size_t idx = (size_t)row * OUTD + tx;
    if (fb) ((unsigned short*)Out)[idx] = f2b(acc);
    else    ((float*)Out)[idx] = acc;
    h2b[idx] = f2b(acc);
  }
}

// ---- agg layer 2 on h2 [N,32] bf16: wave = node, 4 edges x 16 lanes ----
// g2 = A . h2  (same attention). 64B gather per edge instead of 512B.
__global__ __launch_bounds__(256) void agg_small(
    const unsigned short* __restrict__ h2b, const float* __restrict__ coefP,
    const int* __restrict__ srcP, const float* __restrict__ srec,
    const int* __restrict__ offs, unsigned short* __restrict__ g2, int N)
{
  int wid = threadIdx.x >> 6, lane = threadIdx.x & 63;
  int node = blockIdx.x * 4 + wid;
  if (node >= N) return;
  int grp = lane >> 4, cl = lane & 15;
  int s0 = offs[node], s1 = offs[node + 1];
  float a0 = 0.f, a1 = 0.f;
  for (int e = s0 + grp; e < s1; e += 4) {
    int   sv = srcP[e];          // uniform across the 16-lane group (broadcast)
    float wv = coefP[e];
    ushort2 u = *(const ushort2*)(h2b + (size_t)sv * OUTD + cl * 2);
    a0 += wv * b2f(u.x);
    a1 += wv * b2f(u.y);
  }
  // reduce the 4 edge-groups (lane xor 16, 32)
  a0 += __shfl_xor(a0, 16); a0 += __shfl_xor(a0, 32);
  a1 += __shfl_xor(a1, 16); a1 += __shfl_xor(a1, 32);
  if (grp == 0) {
    float inv = 1.f / (srec[node] + 1e-16f);
    ushort2 o; o.x = f2b(a0 * inv); o.y = f2b(a1 * inv);
    *(ushort2*)(g2 + (size_t)node * OUTD + cl * 2) = o;
  }
}

// ---- h3 = elu(g2 @ W2^T) : [N,32] x [32,256] -> bf16 [N,256] ----
// h3[n][c] = elu( sum_j g2[n][j] * W2[c][j] )
__global__ __launch_bounds__(256) void h3_kernel(
    const unsigned short* __restrict__ g2, const float* __restrict__ W2f,
    unsigned short* __restrict__ h3, int N)
{
  __shared__ float swT[32][257];   // swT[j][c] = W2[c][j], padded
  __shared__ float sg[16][32];
  int tid = threadIdx.x;
#pragma unroll
  for (int i = 0; i < 32; ++i) {   // stage W2 (256x32 f32)
    int idx = tid + 256 * i;
    swT[idx & 31][idx >> 5] = W2f[idx];
  }
  int row0 = blockIdx.x * 16;
  {
    int idx = tid * 2;             // stage 16 rows of g2 (bf16 -> f32)
    int r = idx >> 5, j = idx & 31;
    int gr = row0 + r;
    ushort2 u = (gr < N) ? *(const ushort2*)(g2 + (size_t)gr * OUTD + j)
                         : make_ushort2(0, 0);
    sg[r][j] = b2f(u.x);
    sg[r][j + 1] = b2f(u.y);
  }
  __syncthreads();
  int r = tid >> 4, c0 = (tid & 15) * 16;
  float acc[16] = {};
#pragma unroll
  for (int j = 0; j < 32; ++j) {
    float g = sg[r][j];
#pragma unroll
    for (int cc = 0; cc < 16; ++cc) acc[cc] += g * swT[j][c0 + cc];
  }
  int row = row0 + r;
  if (row < N) {
    union { unsigned short us[16]; uint4 v[2]; } pk;
#pragma unroll
    for (int cc = 0; cc < 16; ++cc) {
      float x = acc[cc];
      pk.us[cc] = f2b(x > 0.f ? x : expm1f(x));
    }
    uint4* dst = (uint4*)(h3 + (size_t)row * HIDD + c0);
    dst[0] = pk.v[0];
    dst[1] = pk.v[1];
  }
}

extern "C" void kernel_launch(void* const* d_in, const int* in_sizes, int n_in,
                              void* d_out, int out_size, void* d_ws, size_t ws_size,
                              hipStream_t stream)
{
  const void*         feat = d_in[0];
  const unsigned int* eidx = (const unsigned int*)d_in[1];
  const void*         W1   = d_in[2];
  const void*         W2   = d_in[3];
  const void*         aS   = d_in[4];
  const void*         aD   = d_in[5];

  const int N = in_sizes[0] / INDIM;
  const int E = in_sizes[1] / 2;
  const int M_pad = ((N + 127) / 128) * 128;
  const int nb = (N + 1023) / 1024;

  char* w = (char*)d_ws;
  auto alloc = [&](size_t bytes) -> char* {
    char* p = w; w += (bytes + 255) & ~(size_t)255; return p;
  };
  unsigned short* featb = (unsigned short*)alloc((size_t)M_pad * INDIM * 2); // bf16 features
  unsigned short* H     = featb;   // ALIAS: h1/h3 [M_pad][256] — featb dead after xp1
  unsigned short* P     = (unsigned short*)alloc((size_t)M_pad * HIDD * 2);  // xp1
  unsigned short* h2b   = (unsigned short*)alloc((size_t)N * OUTD * 2);      // h2 bf16
  unsigned short* g2    = (unsigned short*)alloc((size_t)N * OUTD * 2);      // agg(h2) bf16
  float* asrc = (float*)alloc((size_t)N * 4);
  float* adst = (float*)alloc((size_t)N * 4);
  float* srec = (float*)alloc((size_t)N * 4);
  float* coefP = (float*)alloc((size_t)E * 4);   // CSR-ordered edge coef
  int*   srcP  = (int*)alloc((size_t)E * 4);     // CSR-ordered edge src
  int*   deg  = (int*)alloc((size_t)N * 4);
  int*   offs = (int*)alloc((size_t)(N + 1) * 4);
  int*   cur  = (int*)alloc((size_t)N * 4);
  int*   srcN = (int*)alloc((size_t)E * 4);
  int*   dstN = (int*)alloc((size_t)E * 4);
  int*   bsum = (int*)alloc((size_t)(nb + 1) * 4);
  unsigned short* W1b  = (unsigned short*)alloc((size_t)INDIM * HIDD * 2); // [512][256]
  unsigned short* W1tb = (unsigned short*)alloc((size_t)INDIM * HIDD * 2); // [256][512]
  float* W2f  = (float*)alloc((size_t)HIDD * OUTD * 4);
  float* atS  = (float*)alloc((size_t)HIDD * 4);
  float* atD  = (float*)alloc((size_t)HIDD * 4);
  int*   flags = (int*)alloc(64);

  hipMemsetAsync(deg, 0, (size_t)N * 4, stream);
  hipMemsetAsync(srec, 0, (size_t)N * 4, stream);

  probe_kernel<<<1, 256, 0, stream>>>((const unsigned int*)feat, eidx, flags);

  const int eb = (E + 255) / 256;
  convert_idx<<<eb, 256, 0, stream>>>(eidx, srcN, dstN, deg, E, flags);
  prep_weights<<<512, 256, 0, stream>>>(W1, W2, aS, aD, W1b, W1tb, W2f, atS, atD, flags);

  // features -> bf16
  convb_kernel<<<2048, 256, 0, stream>>>(feat, featb, (size_t)N * INDIM / 4, flags);

  const int mb = (N + 127) / 128;

  // xp1 = featb @ W1 : Bt = W1tb [256][512]
  gemm_nt2<0><<<dim3(HIDD / 128, mb), 256, 0, stream>>>(
      featb, W1tb, P, nullptr, 0, flags, N, HIDD, INDIM);

  rowdots<<<(N + 3) / 4, 256, 0, stream>>>(P, atS, atD, asrc, adst, N);

  // CSR offsets (P3 also initializes cur = offs)
  scan_p1<<<nb, 256, 0, stream>>>(deg, bsum, N);
  scan_p2<<<1, 256, 0, stream>>>(bsum, nb);
  scan_p3<<<nb, 256, 0, stream>>>(deg, bsum, offs, cur, N, nb);

  // edge coefficients, CSR-ordered
  fillcoef_kernel<<<eb, 256, 0, stream>>>(srcN, dstN, asrc, adst, cur, srcP, coefP, srec, E);

  // GAT layer 1: h1 = elu(agg(xp1)/denom)   (H aliases featb — featb dead now)
  agg_elu2<<<(N + 3) / 4, 256, 0, stream>>>(P, coefP, srcP, srec, offs, H, N);

  // h2 = h1 @ W2 -> output 0 (+ bf16 copy for layer-2 agg)
  gemm_h2<<<(N + 7) / 8, 256, 0, stream>>>(H, W2f, d_out, h2b, flags, N);

  // GAT layer 2, commuted: g2 = agg(h2) [N,32]  (A·(h2 W2^T) == (A·h2) W2^T)
  agg_small<<<(N + 3) / 4, 256, 0, stream>>>(h2b, coefP, srcP, srec, offs, g2, N);

  // h3 = elu(g2 @ W2^T) [N,256]
  h3_kernel<<<(N + 15) / 16, 256, 0, stream>>>(g2, W2f, H, N);

  // h4 = h3 @ W1^T : Bt = W1b [512][256] -> output 1 (adaptive)
  gemm_nt2<1><<<dim3(INDIM / 128, mb), 256, 0, stream>>>(
      H, W1b, nullptr, d_out, (size_t)N * OUTD, flags, N, INDIM, HIDD);
}

// Round 7
// 786.483 us; speedup vs baseline: 1.5068x; 1.5068x over previous
//
#include <hip/hip_runtime.h>
#include <cstdint>
#include <cstddef>

#define INDIM 512
#define HIDD  256
#define OUTD  32

typedef __attribute__((ext_vector_type(4))) float f32x4;
typedef __attribute__((ext_vector_type(8))) short bf16x8;

// ---- bf16 <-> f32 helpers ----
static inline __device__ float b2f(unsigned short u) {
  union { float f; unsigned int i; } v; v.i = ((unsigned int)u) << 16; return v.f;
}
static inline __device__ unsigned short f2b(float f) {
  union { float f; unsigned int i; } v; v.f = f;
  unsigned int x = v.i;
  x += 0x7fffu + ((x >> 16) & 1u);   // round-to-nearest-even
  return (unsigned short)(x >> 16);
}

// async global->LDS, 16B per lane. LDS dest = wave-uniform base + lane*16.
static __device__ __forceinline__ void gld16(const unsigned short* g, unsigned short* l) {
  __builtin_amdgcn_global_load_lds(
      (const __attribute__((address_space(1))) void*)g,
      (__attribute__((address_space(3))) void*)l, 16, 0, 0);
}

// ---- runtime dtype probe ----
// flags[0] = 1 if float tensors are bf16 on device, 0 if f32
// flags[1] = 1 if edge_index is int64 on device, 0 if int32
__global__ __launch_bounds__(256) void probe_kernel(
    const unsigned int* __restrict__ feat, const unsigned int* __restrict__ eidx,
    int* __restrict__ flags)
{
  int t = threadIdx.x;
  __shared__ int cnt, oddnz;
  if (t == 0) { cnt = 0; oddnz = 0; }
  __syncthreads();
  unsigned int w = feat[t];
  unsigned short lo = (unsigned short)(w & 0xFFFFu);
  int e = (lo >> 7) & 0xFF;
  int plausible = ((lo & 0x7FFF) == 0) || (e >= 0x60 && e <= 0x9F);
  atomicAdd(&cnt, plausible);
  if (t & 1) { if (eidx[t] != 0u) atomicAdd(&oddnz, 1); }
  __syncthreads();
  if (t == 0) { flags[0] = (cnt >= 192) ? 1 : 0; flags[1] = (oddnz == 0) ? 1 : 0; }
}

// ---- edge_index -> int32 src/dst + degree histogram ----
__global__ __launch_bounds__(256) void convert_idx(
    const unsigned int* __restrict__ eidx, int* __restrict__ srcN, int* __restrict__ dstN,
    int* __restrict__ deg, int E, const int* __restrict__ flags)
{
  int ee = blockIdx.x * 256 + threadIdx.x;
  if (ee >= E) return;
  int s, d;
  if (flags[1]) {
    s = (int)eidx[2 * (size_t)ee];
    d = (int)eidx[2 * ((size_t)E + ee)];
  } else {
    s = (int)eidx[ee];
    d = (int)eidx[(size_t)E + ee];
  }
  srcN[ee] = s;
  dstN[ee] = d;
  atomicAdd(&deg[d], 1);
}

static inline __device__ float ldadapt(const void* p, size_t i, int isbf) {
  return isbf ? b2f(((const unsigned short*)p)[i]) : ((const float*)p)[i];
}

// ---- features -> bf16 (or pass-through copy) ----
__global__ __launch_bounds__(256) void convb_kernel(
    const void* __restrict__ in, unsigned short* __restrict__ outb, size_t n4,
    const int* __restrict__ flags)
{
  const int fb = flags[0];
  size_t i = (size_t)blockIdx.x * 256 + threadIdx.x;
  size_t stride = (size_t)gridDim.x * 256;
  if (fb) {
    const ushort4* ip = (const ushort4*)in;
    ushort4* op = (ushort4*)outb;
    for (; i < n4; i += stride) op[i] = ip[i];
  } else {
    const float4* ip = (const float4*)in;
    ushort4* op = (ushort4*)outb;
    for (; i < n4; i += stride) {
      float4 v = ip[i];
      ushort4 o; o.x = f2b(v.x); o.y = f2b(v.y); o.z = f2b(v.z); o.w = f2b(v.w);
      op[i] = o;
    }
  }
}

// ---- weight prep: W1b, W1tb, W2f, W2b64 ([256][64] bf16, zero-padded K), att ----
__global__ __launch_bounds__(256) void prep_weights(
    const void* __restrict__ W1, const void* __restrict__ W2,
    const void* __restrict__ aS, const void* __restrict__ aD,
    unsigned short* __restrict__ W1b, unsigned short* __restrict__ W1tb,
    float* __restrict__ W2f, unsigned short* __restrict__ W2b64,
    float* __restrict__ atS, float* __restrict__ atD,
    const int* __restrict__ flags)
{
  const int fb = flags[0];
  int i = blockIdx.x * 256 + threadIdx.x;
  if (i < INDIM * HIDD) {               // W1: [512][256]
    int r = i >> 8, c = i & 255;
    float w0 = ldadapt(W1, i, fb);
    unsigned short wb = f2b(w0);
    W1b[i] = wb;                        // Bt for h4: [512 rows][256 k]
    W1tb[c * INDIM + r] = wb;           // Bt for xp1: [256 rows][512 k]
  }
  if (i < HIDD * OUTD) {                // W2: [256][32]
    int r = i >> 5, c = i & 31;
    float w0 = ldadapt(W2, i, fb);
    W2f[i] = w0;
    W2b64[r * 64 + c] = f2b(w0);        // Bt for h3: [256 rows][64 k], upper 32 zero
    W2b64[r * 64 + 32 + c] = 0;
  }
  if (i < HIDD) { atS[i] = ldadapt(aS, i, fb); atD[i] = ldadapt(aD, i, fb); }
}

// =====================================================================
// m97-structure MFMA NT GEMM: C[M][Nn] = A[M][K] @ Bt[Nn][K]^T, bf16 in.
// 128x128 tile, BK=64, 4 waves, global_load_lds staging, linear LDS.
// OUTMODE: 0 = bf16 to Cb; 1 = adaptive (flags[0]) to Out+outOff
// EPI:     0 = none; 1 = ELU on the accumulator before store
// =====================================================================
template<int OUTMODE, int EPI>
__global__ __launch_bounds__(256) void gemm_nt2(
    const unsigned short* __restrict__ A, const unsigned short* __restrict__ Bt,
    unsigned short* __restrict__ Cb, void* __restrict__ Out, size_t outOff,
    const int* __restrict__ flags, int M, int Nn, int K)
{
  __shared__ unsigned short Als[128 * 64];
  __shared__ unsigned short Bls[128 * 64];
  const int tid = threadIdx.x, lane = tid & 63, wid = tid >> 6;
  const int wr = wid >> 1, wc = wid & 1;
  const int rowBase = blockIdx.y * 128, colBase = blockIdx.x * 128;
  const int fb = flags[0];

  const int srow = (lane >> 3), sg = lane & 7;

  f32x4 acc[4][4] = {};

  for (int kt = 0; kt < K; kt += 64) {
#pragma unroll
    for (int i = 0; i < 4; ++i) {
      int row = wid * 32 + i * 8 + srow;
      gld16(A + (size_t)(rowBase + row) * K + kt + sg * 8, Als + (wid * 4 + i) * 512);
      gld16(Bt + (size_t)(colBase + row) * K + kt + sg * 8, Bls + (wid * 4 + i) * 512);
    }
    __syncthreads();

    bf16x8 af[4], bfr[4];
#pragma unroll
    for (int ks = 0; ks < 2; ++ks) {
      int g = ks * 4 + (lane >> 4);
#pragma unroll
      for (int mi = 0; mi < 4; ++mi) {
        int row = wr * 64 + mi * 16 + (lane & 15);
        af[mi] = *(const bf16x8*)(Als + row * 64 + g * 8);
      }
#pragma unroll
      for (int ni = 0; ni < 4; ++ni) {
        int row = wc * 64 + ni * 16 + (lane & 15);
        bfr[ni] = *(const bf16x8*)(Bls + row * 64 + g * 8);
      }
#pragma unroll
      for (int mi = 0; mi < 4; ++mi)
#pragma unroll
        for (int ni = 0; ni < 4; ++ni)
          acc[mi][ni] = __builtin_amdgcn_mfma_f32_16x16x32_bf16(af[mi], bfr[ni], acc[mi][ni], 0, 0, 0);
    }
    __syncthreads();
  }

  // C/D: col = lane&15, row = (lane>>4)*4 + reg
#pragma unroll
  for (int mi = 0; mi < 4; ++mi) {
    int r0 = rowBase + wr * 64 + mi * 16 + (lane >> 4) * 4;
#pragma unroll
    for (int ni = 0; ni < 4; ++ni) {
      int c = colBase + wc * 64 + ni * 16 + (lane & 15);
#pragma unroll
      for (int v = 0; v < 4; ++v) {
        int r = r0 + v;
        if (r < M) {
          size_t idx = (size_t)r * Nn + c;
          float x = acc[mi][ni][v];
          if (EPI) x = x > 0.f ? x : expm1f(x);
          if (OUTMODE == 0) Cb[idx] = f2b(x);
          else {
            if (fb) ((unsigned short*)Out)[outOff + idx] = f2b(x);
            else    ((float*)Out)[outOff + idx] = x;
          }
        }
      }
    }
  }
}

// ---- a_src / a_dst: one wave per node, dot(xp1_row, att); P is bf16 ----
__global__ __launch_bounds__(256) void rowdots(
    const unsigned short* __restrict__ P, const float* __restrict__ atS,
    const float* __restrict__ atD,
    float* __restrict__ asrc, float* __restrict__ adst, int N)
{
  int wave = threadIdx.x >> 6, lane = threadIdx.x & 63;
  int node = blockIdx.x * 4 + wave;
  if (node >= N) return;
  ushort4 u = *(const ushort4*)(P + (size_t)node * HIDD + lane * 4);
  float4 v = make_float4(b2f(u.x), b2f(u.y), b2f(u.z), b2f(u.w));
  float4 s = *(const float4*)(atS + lane * 4);
  float4 d = *(const float4*)(atD + lane * 4);
  float s1 = v.x * s.x + v.y * s.y + v.z * s.z + v.w * s.w;
  float s2 = v.x * d.x + v.y * d.y + v.z * d.z + v.w * d.w;
#pragma unroll
  for (int off = 32; off; off >>= 1) {
    s1 += __shfl_down(s1, off);
    s2 += __shfl_down(s2, off);
  }
  if (lane == 0) { asrc[node] = s1; adst[node] = s2; }
}

// ---- multi-block exclusive scan ----
__global__ __launch_bounds__(256) void scan_p1(const int* __restrict__ deg,
                                               int* __restrict__ bsum, int N)
{
  int b = blockIdx.x, t = threadIdx.x;
  int i0 = b * 1024 + t * 4;
  int s = 0;
#pragma unroll
  for (int j = 0; j < 4; ++j) { int i = i0 + j; if (i < N) s += deg[i]; }
  __shared__ int red[256];
  red[t] = s;
  __syncthreads();
  for (int o = 128; o; o >>= 1) {
    if (t < o) red[t] += red[t + o];
    __syncthreads();
  }
  if (t == 0) bsum[b] = red[0];
}

__global__ __launch_bounds__(256) void scan_p2(int* __restrict__ bsum, int nb)
{
  __shared__ int sh[256];
  int t = threadIdx.x;
  int v = (t < nb) ? bsum[t] : 0;
  sh[t] = v;
  __syncthreads();
  for (int o = 1; o < 256; o <<= 1) {
    int u = (t >= o) ? sh[t - o] : 0;
    __syncthreads();
    sh[t] += u;
    __syncthreads();
  }
  if (t < nb) bsum[t] = sh[t] - v;   // exclusive
}

__global__ __launch_bounds__(256) void scan_p3(const int* __restrict__ deg,
                                               const int* __restrict__ bsum,
                                               int* __restrict__ offs, int* __restrict__ cur,
                                               int N, int nb)
{
  int b = blockIdx.x, t = threadIdx.x;
  int i0 = b * 1024 + t * 4;
  int v[4]; int s = 0;
#pragma unroll
  for (int j = 0; j < 4; ++j) { int i = i0 + j; v[j] = (i < N) ? deg[i] : 0; s += v[j]; }
  __shared__ int sh[256];
  sh[t] = s;
  __syncthreads();
  for (int o = 1; o < 256; o <<= 1) {
    int u = (t >= o) ? sh[t - o] : 0;
    __syncthreads();
    sh[t] += u;
    __syncthreads();
  }
  int run = bsum[b] + sh[t] - s;
#pragma unroll
  for (int j = 0; j < 4; ++j) {
    int i = i0 + j;
    if (i < N) { offs[i] = run; cur[i] = run; }
    run += v[j];
  }
  if (b == nb - 1 && t == 255) offs[N] = run;   // total = E
}

// ---- fused fill+coef: CSR-ordered srcP/coefP + denominator atomics ----
__global__ __launch_bounds__(256) void fillcoef_kernel(
    const int* __restrict__ srcN, const int* __restrict__ dstN,
    const float* __restrict__ asrc, const float* __restrict__ adst,
    int* __restrict__ cur, int* __restrict__ srcP, float* __restrict__ coefP,
    float* __restrict__ srec, int E)
{
  int e = blockIdx.x * 256 + threadIdx.x;
  if (e >= E) return;
  int s = srcN[e], d = dstN[e];
  float x = asrc[s] + adst[d];
  float al = 1.f / (1.f + __expf(-x));    // sigmoid in (0,1): segment-max unneeded
  float t = __expf(al);
  int pos = atomicAdd(&cur[d], 1);
  srcP[pos] = s;
  coefP[pos] = t;
  atomicAdd(&srec[d], t);
}

// ---- agg layer 1: wave per node, 4 ch/lane, 8 gathers in flight, /denom + ELU ----
__global__ __launch_bounds__(256) void agg_elu2(
    const unsigned short* __restrict__ xp, const float* __restrict__ coefP,
    const int* __restrict__ srcP, const float* __restrict__ srec,
    const int* __restrict__ offs, unsigned short* __restrict__ hout, int N)
{
  __shared__ int   sS[4][64];
  __shared__ float sW[4][64];
  int wid = threadIdx.x >> 6, lane = threadIdx.x & 63;
  int node = blockIdx.x * 4 + wid;
  if (node >= N) return;
  int s0 = offs[node], s1 = offs[node + 1];
  float a0 = 0.f, a1 = 0.f, a2 = 0.f, a3 = 0.f;
  for (int base = s0; base < s1; base += 64) {
    int cnt = s1 - base; if (cnt > 64) cnt = 64;
    if (lane < cnt) {
      sS[wid][lane] = srcP[base + lane];
      sW[wid][lane] = coefP[base + lane];
    }
    asm volatile("s_waitcnt lgkmcnt(0)" ::: "memory");   // wave-local LDS RAW fence
    int j = 0;
    for (; j + 8 <= cnt; j += 8) {
      ushort4 u[8];
#pragma unroll
      for (int q = 0; q < 8; ++q)
        u[q] = *(const ushort4*)(xp + (size_t)sS[wid][j + q] * HIDD + lane * 4);
#pragma unroll
      for (int q = 0; q < 8; ++q) {
        float wv = sW[wid][j + q];
        a0 += wv * b2f(u[q].x); a1 += wv * b2f(u[q].y);
        a2 += wv * b2f(u[q].z); a3 += wv * b2f(u[q].w);
      }
    }
    for (; j < cnt; ++j) {
      int   sv = sS[wid][j];
      float wv = sW[wid][j];
      ushort4 u = *(const ushort4*)(xp + (size_t)sv * HIDD + lane * 4);
      a0 += wv * b2f(u.x); a1 += wv * b2f(u.y); a2 += wv * b2f(u.z); a3 += wv * b2f(u.w);
    }
  }
  float inv = 1.f / (srec[node] + 1e-16f);
  float r0 = a0 * inv, r1 = a1 * inv, r2 = a2 * inv, r3 = a3 * inv;
  r0 = r0 > 0.f ? r0 : expm1f(r0);
  r1 = r1 > 0.f ? r1 : expm1f(r1);
  r2 = r2 > 0.f ? r2 : expm1f(r2);
  r3 = r3 > 0.f ? r3 : expm1f(r3);
  ushort4 o; o.x = f2b(r0); o.y = f2b(r1); o.z = f2b(r2); o.w = f2b(r3);
  *(ushort4*)(hout + (size_t)node * HIDD + lane * 4) = o;
}

// ---- h2 = h1 @ W2 ([N,256]x[256,32]) -> adaptive out + bf16 copy ----
__global__ __launch_bounds__(256) void gemm_h2(
    const unsigned short* __restrict__ H1, const float* __restrict__ W2f,
    void* __restrict__ Out, unsigned short* __restrict__ h2b,
    const int* __restrict__ flags, int M)
{
  const int fb = flags[0];
  __shared__ float Bs[HIDD][33];
  __shared__ float As[8][HIDD];
  int tid = threadIdx.x;
  int tx = tid & 31, ty = tid >> 5;
  int row0 = blockIdx.x * 8;
#pragma unroll
  for (int j = 0; j < 32; ++j) {
    int idx = tid + 256 * j;
    Bs[idx >> 5][idx & 31] = W2f[idx];
  }
#pragma unroll
  for (int j = 0; j < 8; ++j) {
    int idx = tid + 256 * j;
    int r = idx >> 8, k = idx & 255;
    As[r][k] = (row0 + r < M) ? b2f(H1[(size_t)(row0 + r) * HIDD + k]) : 0.f;
  }
  __syncthreads();
  float acc = 0.f;
#pragma unroll 8
  for (int k = 0; k < HIDD; ++k) acc += As[ty][k] * Bs[k][tx];
  int row = row0 + ty;
  if (row < M) {
    size_t idx = (size_t)row * OUTD + tx;
    if (fb) ((unsigned short*)Out)[idx] = f2b(acc);
    else    ((float*)Out)[idx] = acc;
    h2b[idx] = f2b(acc);
  }
}

// ---- agg layer 2 on h2 [N,32] bf16 -> g2pad [N][64] (upper 32 zeroed) ----
__global__ __launch_bounds__(256) void agg_small(
    const unsigned short* __restrict__ h2b, const float* __restrict__ coefP,
    const int* __restrict__ srcP, const float* __restrict__ srec,
    const int* __restrict__ offs, unsigned short* __restrict__ g2pad, int N)
{
  int wid = threadIdx.x >> 6, lane = threadIdx.x & 63;
  int node = blockIdx.x * 4 + wid;
  if (node >= N) return;
  int grp = lane >> 4, cl = lane & 15;
  int s0 = offs[node], s1 = offs[node + 1];
  float a0 = 0.f, a1 = 0.f;
  for (int e = s0 + grp; e < s1; e += 4) {
    int   sv = srcP[e];          // uniform across the 16-lane group (broadcast)
    float wv = coefP[e];
    ushort2 u = *(const ushort2*)(h2b + (size_t)sv * OUTD + cl * 2);
    a0 += wv * b2f(u.x);
    a1 += wv * b2f(u.y);
  }
  // reduce the 4 edge-groups (lane xor 16, 32)
  a0 += __shfl_xor(a0, 16); a0 += __shfl_xor(a0, 32);
  a1 += __shfl_xor(a1, 16); a1 += __shfl_xor(a1, 32);
  if (grp == 0) {
    float inv = 1.f / (srec[node] + 1e-16f);
    ushort2 o; o.x = f2b(a0 * inv); o.y = f2b(a1 * inv);
    *(ushort2*)(g2pad + (size_t)node * 64 + cl * 2) = o;
  } else if (grp == 1) {
    *(ushort2*)(g2pad + (size_t)node * 64 + 32 + cl * 2) = make_ushort2(0, 0);  // K-pad
  }
}

extern "C" void kernel_launch(void* const* d_in, const int* in_sizes, int n_in,
                              void* d_out, int out_size, void* d_ws, size_t ws_size,
                              hipStream_t stream)
{
  const void*         feat = d_in[0];
  const unsigned int* eidx = (const unsigned int*)d_in[1];
  const void*         W1   = d_in[2];
  const void*         W2   = d_in[3];
  const void*         aS   = d_in[4];
  const void*         aD   = d_in[5];

  const int N = in_sizes[0] / INDIM;
  const int E = in_sizes[1] / 2;
  const int M_pad = ((N + 127) / 128) * 128;
  const int nb = (N + 1023) / 1024;

  char* w = (char*)d_ws;
  auto alloc = [&](size_t bytes) -> char* {
    char* p = w; w += (bytes + 255) & ~(size_t)255; return p;
  };
  unsigned short* featb = (unsigned short*)alloc((size_t)M_pad * INDIM * 2); // bf16 features
  unsigned short* H     = featb;   // ALIAS: h1/h3 [M_pad][256] — featb dead after xp1
  unsigned short* P     = (unsigned short*)alloc((size_t)M_pad * HIDD * 2);  // xp1
  unsigned short* h2b   = (unsigned short*)alloc((size_t)N * OUTD * 2);      // h2 bf16
  unsigned short* g2pad = (unsigned short*)alloc((size_t)M_pad * 64 * 2);    // agg(h2), K-padded
  float* asrc = (float*)alloc((size_t)N * 4);
  float* adst = (float*)alloc((size_t)N * 4);
  float* srec = (float*)alloc((size_t)N * 4);
  float* coefP = (float*)alloc((size_t)E * 4);   // CSR-ordered edge coef
  int*   srcP  = (int*)alloc((size_t)E * 4);     // CSR-ordered edge src
  int*   deg  = (int*)alloc((size_t)N * 4);
  int*   offs = (int*)alloc((size_t)(N + 1) * 4);
  int*   cur  = (int*)alloc((size_t)N * 4);
  int*   srcN = (int*)alloc((size_t)E * 4);
  int*   dstN = (int*)alloc((size_t)E * 4);
  int*   bsum = (int*)alloc((size_t)(nb + 1) * 4);
  unsigned short* W1b   = (unsigned short*)alloc((size_t)INDIM * HIDD * 2); // [512][256]
  unsigned short* W1tb  = (unsigned short*)alloc((size_t)INDIM * HIDD * 2); // [256][512]
  unsigned short* W2b64 = (unsigned short*)alloc((size_t)HIDD * 64 * 2);    // [256][64]
  float* W2f  = (float*)alloc((size_t)HIDD * OUTD * 4);
  float* atS  = (float*)alloc((size_t)HIDD * 4);
  float* atD  = (float*)alloc((size_t)HIDD * 4);
  int*   flags = (int*)alloc(64);

  hipMemsetAsync(deg, 0, (size_t)N * 4, stream);
  hipMemsetAsync(srec, 0, (size_t)N * 4, stream);

  probe_kernel<<<1, 256, 0, stream>>>((const unsigned int*)feat, eidx, flags);

  const int eb = (E + 255) / 256;
  convert_idx<<<eb, 256, 0, stream>>>(eidx, srcN, dstN, deg, E, flags);
  prep_weights<<<512, 256, 0, stream>>>(W1, W2, aS, aD, W1b, W1tb, W2f, W2b64, atS, atD, flags);

  // features -> bf16
  convb_kernel<<<2048, 256, 0, stream>>>(feat, featb, (size_t)N * INDIM / 4, flags);

  const int mb = (N + 127) / 128;

  // xp1 = featb @ W1 : Bt = W1tb [256][512]
  gemm_nt2<0, 0><<<dim3(HIDD / 128, mb), 256, 0, stream>>>(
      featb, W1tb, P, nullptr, 0, flags, N, HIDD, INDIM);

  rowdots<<<(N + 3) / 4, 256, 0, stream>>>(P, atS, atD, asrc, adst, N);

  // CSR offsets (P3 also initializes cur = offs)
  scan_p1<<<nb, 256, 0, stream>>>(deg, bsum, N);
  scan_p2<<<1, 256, 0, stream>>>(bsum, nb);
  scan_p3<<<nb, 256, 0, stream>>>(deg, bsum, offs, cur, N, nb);

  // edge coefficients, CSR-ordered
  fillcoef_kernel<<<eb, 256, 0, stream>>>(srcN, dstN, asrc, adst, cur, srcP, coefP, srec, E);

  // GAT layer 1: h1 = elu(agg(xp1)/denom)   (H aliases featb — featb dead now)
  agg_elu2<<<(N + 3) / 4, 256, 0, stream>>>(P, coefP, srcP, srec, offs, H, N);

  // h2 = h1 @ W2 -> output 0 (+ bf16 copy for layer-2 agg)
  gemm_h2<<<(N + 7) / 8, 256, 0, stream>>>(H, W2f, d_out, h2b, flags, N);

  // GAT layer 2, commuted: g2 = agg(h2) [N,32->64pad]  (A·(h2 W2^T) == (A·h2) W2^T)
  agg_small<<<(N + 3) / 4, 256, 0, stream>>>(h2b, coefP, srcP, srec, offs, g2pad, N);

  // h3 = elu(g2 @ W2^T) via MFMA GEMM: A = g2pad [M,64], Bt = W2b64 [256][64]
  gemm_nt2<0, 1><<<dim3(HIDD / 128, mb), 256, 0, stream>>>(
      g2pad, W2b64, H, nullptr, 0, flags, N, HIDD, 64);

  // h4 = h3 @ W1^T : Bt = W1b [512][256] -> output 1 (adaptive)
  gemm_nt2<1, 0><<<dim3(INDIM / 128, mb), 256, 0, stream>>>(
      H, W1b, nullptr, d_out, (size_t)N * OUTD, flags, N, INDIM, HIDD);
}

// Round 8
// 730.197 us; speedup vs baseline: 1.6229x; 1.0771x over previous
//
#include <hip/hip_runtime.h>
#include <cstdint>
#include <cstddef>

#define INDIM 512
#define HIDD  256
#define OUTD  32

typedef __attribute__((ext_vector_type(4))) float f32x4;
typedef __attribute__((ext_vector_type(8))) short bf16x8;

// ---- bf16 <-> f32 helpers ----
static inline __device__ float b2f(unsigned short u) {
  union { float f; unsigned int i; } v; v.i = ((unsigned int)u) << 16; return v.f;
}
static inline __device__ unsigned short f2b(float f) {
  union { float f; unsigned int i; } v; v.f = f;
  unsigned int x = v.i;
  x += 0x7fffu + ((x >> 16) & 1u);   // round-to-nearest-even
  return (unsigned short)(x >> 16);
}

// edge weight: exp(sigmoid(x)) — must be the SAME formula in both agg kernels
static inline __device__ float edgew(float x) {
  float al = 1.f / (1.f + __expf(-x));
  return __expf(al);
}

// async global->LDS, 16B per lane. LDS dest = wave-uniform base + lane*16.
static __device__ __forceinline__ void gld16(const unsigned short* g, unsigned short* l) {
  __builtin_amdgcn_global_load_lds(
      (const __attribute__((address_space(1))) void*)g,
      (__attribute__((address_space(3))) void*)l, 16, 0, 0);
}

// ---- runtime dtype probe ----
// flags[0] = 1 if float tensors are bf16 on device, 0 if f32
// flags[1] = 1 if edge_index is int64 on device, 0 if int32
__global__ __launch_bounds__(256) void probe_kernel(
    const unsigned int* __restrict__ feat, const unsigned int* __restrict__ eidx,
    int* __restrict__ flags)
{
  int t = threadIdx.x;
  __shared__ int cnt, oddnz;
  if (t == 0) { cnt = 0; oddnz = 0; }
  __syncthreads();
  unsigned int w = feat[t];
  unsigned short lo = (unsigned short)(w & 0xFFFFu);
  int e = (lo >> 7) & 0xFF;
  int plausible = ((lo & 0x7FFF) == 0) || (e >= 0x60 && e <= 0x9F);
  atomicAdd(&cnt, plausible);
  if (t & 1) { if (eidx[t] != 0u) atomicAdd(&oddnz, 1); }
  __syncthreads();
  if (t == 0) { flags[0] = (cnt >= 192) ? 1 : 0; flags[1] = (oddnz == 0) ? 1 : 0; }
}

// ---- degree histogram straight from edge_index ----
__global__ __launch_bounds__(256) void deg_kernel(
    const unsigned int* __restrict__ eidx, int* __restrict__ deg, int E,
    const int* __restrict__ flags)
{
  int e = blockIdx.x * 256 + threadIdx.x;
  if (e >= E) return;
  int d = flags[1] ? (int)eidx[2 * ((size_t)E + e)] : (int)eidx[(size_t)E + e];
  atomicAdd(&deg[d], 1);
}

static inline __device__ float ldadapt(const void* p, size_t i, int isbf) {
  return isbf ? b2f(((const unsigned short*)p)[i]) : ((const float*)p)[i];
}

// ---- features -> bf16 (or pass-through copy) ----
__global__ __launch_bounds__(256) void convb_kernel(
    const void* __restrict__ in, unsigned short* __restrict__ outb, size_t n4,
    const int* __restrict__ flags)
{
  const int fb = flags[0];
  size_t i = (size_t)blockIdx.x * 256 + threadIdx.x;
  size_t stride = (size_t)gridDim.x * 256;
  if (fb) {
    const ushort4* ip = (const ushort4*)in;
    ushort4* op = (ushort4*)outb;
    for (; i < n4; i += stride) op[i] = ip[i];
  } else {
    const float4* ip = (const float4*)in;
    ushort4* op = (ushort4*)outb;
    for (; i < n4; i += stride) {
      float4 v = ip[i];
      ushort4 o; o.x = f2b(v.x); o.y = f2b(v.y); o.z = f2b(v.z); o.w = f2b(v.w);
      op[i] = o;
    }
  }
}

// ---- weight prep: W1b, W1tb, W2f, W2b64 ([256][64] bf16, zero-padded K), att ----
__global__ __launch_bounds__(256) void prep_weights(
    const void* __restrict__ W1, const void* __restrict__ W2,
    const void* __restrict__ aS, const void* __restrict__ aD,
    unsigned short* __restrict__ W1b, unsigned short* __restrict__ W1tb,
    float* __restrict__ W2f, unsigned short* __restrict__ W2b64,
    float* __restrict__ atS, float* __restrict__ atD,
    const int* __restrict__ flags)
{
  const int fb = flags[0];
  int i = blockIdx.x * 256 + threadIdx.x;
  if (i < INDIM * HIDD) {               // W1: [512][256]
    int r = i >> 8, c = i & 255;
    float w0 = ldadapt(W1, i, fb);
    unsigned short wb = f2b(w0);
    W1b[i] = wb;                        // Bt for h4: [512 rows][256 k]
    W1tb[c * INDIM + r] = wb;           // Bt for xp1: [256 rows][512 k]
  }
  if (i < HIDD * OUTD) {                // W2: [256][32]
    int r = i >> 5, c = i & 31;
    float w0 = ldadapt(W2, i, fb);
    W2f[i] = w0;
    W2b64[r * 64 + c] = f2b(w0);        // Bt for h3: [256 rows][64 k], upper 32 zero
    W2b64[r * 64 + 32 + c] = 0;
  }
  if (i < HIDD) { atS[i] = ldadapt(aS, i, fb); atD[i] = ldadapt(aD, i, fb); }
}

// =====================================================================
// m97-structure MFMA NT GEMM: C[M][Nn] = A[M][K] @ Bt[Nn][K]^T, bf16 in.
// OUTMODE: 0 = bf16 to Cb; 1 = adaptive (flags[0]) to Out+outOff
// EPI:     0 = none; 1 = ELU before store
// =====================================================================
template<int OUTMODE, int EPI>
__global__ __launch_bounds__(256) void gemm_nt2(
    const unsigned short* __restrict__ A, const unsigned short* __restrict__ Bt,
    unsigned short* __restrict__ Cb, void* __restrict__ Out, size_t outOff,
    const int* __restrict__ flags, int M, int Nn, int K)
{
  __shared__ unsigned short Als[128 * 64];
  __shared__ unsigned short Bls[128 * 64];
  const int tid = threadIdx.x, lane = tid & 63, wid = tid >> 6;
  const int wr = wid >> 1, wc = wid & 1;
  const int rowBase = blockIdx.y * 128, colBase = blockIdx.x * 128;
  const int fb = flags[0];

  const int srow = (lane >> 3), sg = lane & 7;

  f32x4 acc[4][4] = {};

  for (int kt = 0; kt < K; kt += 64) {
#pragma unroll
    for (int i = 0; i < 4; ++i) {
      int row = wid * 32 + i * 8 + srow;
      gld16(A + (size_t)(rowBase + row) * K + kt + sg * 8, Als + (wid * 4 + i) * 512);
      gld16(Bt + (size_t)(colBase + row) * K + kt + sg * 8, Bls + (wid * 4 + i) * 512);
    }
    __syncthreads();

    bf16x8 af[4], bfr[4];
#pragma unroll
    for (int ks = 0; ks < 2; ++ks) {
      int g = ks * 4 + (lane >> 4);
#pragma unroll
      for (int mi = 0; mi < 4; ++mi) {
        int row = wr * 64 + mi * 16 + (lane & 15);
        af[mi] = *(const bf16x8*)(Als + row * 64 + g * 8);
      }
#pragma unroll
      for (int ni = 0; ni < 4; ++ni) {
        int row = wc * 64 + ni * 16 + (lane & 15);
        bfr[ni] = *(const bf16x8*)(Bls + row * 64 + g * 8);
      }
#pragma unroll
      for (int mi = 0; mi < 4; ++mi)
#pragma unroll
        for (int ni = 0; ni < 4; ++ni)
          acc[mi][ni] = __builtin_amdgcn_mfma_f32_16x16x32_bf16(af[mi], bfr[ni], acc[mi][ni], 0, 0, 0);
    }
    __syncthreads();
  }

  // C/D: col = lane&15, row = (lane>>4)*4 + reg
#pragma unroll
  for (int mi = 0; mi < 4; ++mi) {
    int r0 = rowBase + wr * 64 + mi * 16 + (lane >> 4) * 4;
#pragma unroll
    for (int ni = 0; ni < 4; ++ni) {
      int c = colBase + wc * 64 + ni * 16 + (lane & 15);
#pragma unroll
      for (int v = 0; v < 4; ++v) {
        int r = r0 + v;
        if (r < M) {
          size_t idx = (size_t)r * Nn + c;
          float x = acc[mi][ni][v];
          if (EPI) x = x > 0.f ? x : expm1f(x);
          if (OUTMODE == 0) Cb[idx] = f2b(x);
          else {
            if (fb) ((unsigned short*)Out)[outOff + idx] = f2b(x);
            else    ((float*)Out)[outOff + idx] = x;
          }
        }
      }
    }
  }
}

// ---- a_src / a_dst: one wave per node, dot(xp1_row, att); P is bf16 ----
__global__ __launch_bounds__(256) void rowdots(
    const unsigned short* __restrict__ P, const float* __restrict__ atS,
    const float* __restrict__ atD,
    float* __restrict__ asrc, float* __restrict__ adst, int N)
{
  int wave = threadIdx.x >> 6, lane = threadIdx.x & 63;
  int node = blockIdx.x * 4 + wave;
  if (node >= N) return;
  ushort4 u = *(const ushort4*)(P + (size_t)node * HIDD + lane * 4);
  float4 v = make_float4(b2f(u.x), b2f(u.y), b2f(u.z), b2f(u.w));
  float4 s = *(const float4*)(atS + lane * 4);
  float4 d = *(const float4*)(atD + lane * 4);
  float s1 = v.x * s.x + v.y * s.y + v.z * s.z + v.w * s.w;
  float s2 = v.x * d.x + v.y * d.y + v.z * d.z + v.w * d.w;
#pragma unroll
  for (int off = 32; off; off >>= 1) {
    s1 += __shfl_down(s1, off);
    s2 += __shfl_down(s2, off);
  }
  if (lane == 0) { asrc[node] = s1; adst[node] = s2; }
}

// ---- multi-block exclusive scan ----
__global__ __launch_bounds__(256) void scan_p1(const int* __restrict__ deg,
                                               int* __restrict__ bsum, int N)
{
  int b = blockIdx.x, t = threadIdx.x;
  int i0 = b * 1024 + t * 4;
  int s = 0;
#pragma unroll
  for (int j = 0; j < 4; ++j) { int i = i0 + j; if (i < N) s += deg[i]; }
  __shared__ int red[256];
  red[t] = s;
  __syncthreads();
  for (int o = 128; o; o >>= 1) {
    if (t < o) red[t] += red[t + o];
    __syncthreads();
  }
  if (t == 0) bsum[b] = red[0];
}

__global__ __launch_bounds__(256) void scan_p2(int* __restrict__ bsum, int nb)
{
  __shared__ int sh[256];
  int t = threadIdx.x;
  int v = (t < nb) ? bsum[t] : 0;
  sh[t] = v;
  __syncthreads();
  for (int o = 1; o < 256; o <<= 1) {
    int u = (t >= o) ? sh[t - o] : 0;
    __syncthreads();
    sh[t] += u;
    __syncthreads();
  }
  if (t < nb) bsum[t] = sh[t] - v;   // exclusive
}

__global__ __launch_bounds__(256) void scan_p3(const int* __restrict__ deg,
                                               const int* __restrict__ bsum,
                                               int* __restrict__ offs, int* __restrict__ cur,
                                               int N, int nb)
{
  int b = blockIdx.x, t = threadIdx.x;
  int i0 = b * 1024 + t * 4;
  int v[4]; int s = 0;
#pragma unroll
  for (int j = 0; j < 4; ++j) { int i = i0 + j; v[j] = (i < N) ? deg[i] : 0; s += v[j]; }
  __shared__ int sh[256];
  sh[t] = s;
  __syncthreads();
  for (int o = 1; o < 256; o <<= 1) {
    int u = (t >= o) ? sh[t - o] : 0;
    __syncthreads();
    sh[t] += u;
    __syncthreads();
  }
  int run = bsum[b] + sh[t] - s;
#pragma unroll
  for (int j = 0; j < 4; ++j) {
    int i = i0 + j;
    if (i < N) { offs[i] = run; cur[i] = run; }
    run += v[j];
  }
  if (b == nb - 1 && t == 255) offs[N] = run;   // total = E
}

// ---- CSR fill: scatter ONLY the source index (4B/edge) ----
__global__ __launch_bounds__(256) void fill_kernel(
    const unsigned int* __restrict__ eidx, int* __restrict__ cur,
    int* __restrict__ srcP, int E, const int* __restrict__ flags)
{
  int e = blockIdx.x * 256 + threadIdx.x;
  if (e >= E) return;
  int s, d;
  if (flags[1]) {
    s = (int)eidx[2 * (size_t)e];
    d = (int)eidx[2 * ((size_t)E + e)];
  } else {
    s = (int)eidx[e];
    d = (int)eidx[(size_t)E + e];
  }
  int pos = atomicAdd(&cur[d], 1);
  srcP[pos] = s;
}

// ---- agg layer 1: wave/node, w computed at stage time, denominator in-loop ----
__global__ __launch_bounds__(256) void agg_elu2(
    const unsigned short* __restrict__ xp,
    const float* __restrict__ asrc, const float* __restrict__ adst,
    const int* __restrict__ srcP, const int* __restrict__ offs,
    unsigned short* __restrict__ hout, int N)
{
  __shared__ int   sS[4][64];
  __shared__ float sW[4][64];
  int wid = threadIdx.x >> 6, lane = threadIdx.x & 63;
  int node = blockIdx.x * 4 + wid;
  if (node >= N) return;
  const float ad = adst[node];
  int s0 = offs[node], s1 = offs[node + 1];
  float a0 = 0.f, a1 = 0.f, a2 = 0.f, a3 = 0.f, den = 0.f;
  for (int base = s0; base < s1; base += 64) {
    int cnt = s1 - base; if (cnt > 64) cnt = 64;
    if (lane < cnt) {
      int sv = srcP[base + lane];
      sS[wid][lane] = sv;
      sW[wid][lane] = edgew(asrc[sv] + ad);
    }
    asm volatile("s_waitcnt lgkmcnt(0)" ::: "memory");   // wave-local LDS RAW fence
    int j = 0;
    for (; j + 8 <= cnt; j += 8) {
      ushort4 u[8];
#pragma unroll
      for (int q = 0; q < 8; ++q)
        u[q] = *(const ushort4*)(xp + (size_t)sS[wid][j + q] * HIDD + lane * 4);
#pragma unroll
      for (int q = 0; q < 8; ++q) {
        float wv = sW[wid][j + q];
        den += wv;
        a0 += wv * b2f(u[q].x); a1 += wv * b2f(u[q].y);
        a2 += wv * b2f(u[q].z); a3 += wv * b2f(u[q].w);
      }
    }
    for (; j < cnt; ++j) {
      int   sv = sS[wid][j];
      float wv = sW[wid][j];
      den += wv;
      ushort4 u = *(const ushort4*)(xp + (size_t)sv * HIDD + lane * 4);
      a0 += wv * b2f(u.x); a1 += wv * b2f(u.y); a2 += wv * b2f(u.z); a3 += wv * b2f(u.w);
    }
  }
  float inv = 1.f / (den + 1e-16f);
  float r0 = a0 * inv, r1 = a1 * inv, r2 = a2 * inv, r3 = a3 * inv;
  r0 = r0 > 0.f ? r0 : expm1f(r0);
  r1 = r1 > 0.f ? r1 : expm1f(r1);
  r2 = r2 > 0.f ? r2 : expm1f(r2);
  r3 = r3 > 0.f ? r3 : expm1f(r3);
  ushort4 o; o.x = f2b(r0); o.y = f2b(r1); o.z = f2b(r2); o.w = f2b(r3);
  *(ushort4*)(hout + (size_t)node * HIDD + lane * 4) = o;
}

// ---- h2 = h1 @ W2 ([N,256]x[256,32]) -> adaptive out + bf16 copy ----
__global__ __launch_bounds__(256) void gemm_h2(
    const unsigned short* __restrict__ H1, const float* __restrict__ W2f,
    void* __restrict__ Out, unsigned short* __restrict__ h2b,
    const int* __restrict__ flags, int M)
{
  const int fb = flags[0];
  __shared__ float Bs[HIDD][33];
  __shared__ float As[8][HIDD];
  int tid = threadIdx.x;
  int tx = tid & 31, ty = tid >> 5;
  int row0 = blockIdx.x * 8;
#pragma unroll
  for (int j = 0; j < 32; ++j) {
    int idx = tid + 256 * j;
    Bs[idx >> 5][idx & 31] = W2f[idx];
  }
#pragma unroll
  for (int j = 0; j < 8; ++j) {
    int idx = tid + 256 * j;
    int r = idx >> 8, k = idx & 255;
    As[r][k] = (row0 + r < M) ? b2f(H1[(size_t)(row0 + r) * HIDD + k]) : 0.f;
  }
  __syncthreads();
  float acc = 0.f;
#pragma unroll 8
  for (int k = 0; k < HIDD; ++k) acc += As[ty][k] * Bs[k][tx];
  int row = row0 + ty;
  if (row < M) {
    size_t idx = (size_t)row * OUTD + tx;
    if (fb) ((unsigned short*)Out)[idx] = f2b(acc);
    else    ((float*)Out)[idx] = acc;
    h2b[idx] = f2b(acc);
  }
}

// ---- agg layer 2 on h2 [N,32] bf16 -> g2pad [N][64], w recomputed inline ----
__global__ __launch_bounds__(256) void agg_small(
    const unsigned short* __restrict__ h2b,
    const float* __restrict__ asrc, const float* __restrict__ adst,
    const int* __restrict__ srcP, const int* __restrict__ offs,
    unsigned short* __restrict__ g2pad, int N)
{
  int wid = threadIdx.x >> 6, lane = threadIdx.x & 63;
  int node = blockIdx.x * 4 + wid;
  if (node >= N) return;
  int grp = lane >> 4, cl = lane & 15;
  const float ad = adst[node];
  int s0 = offs[node], s1 = offs[node + 1];
  float a0 = 0.f, a1 = 0.f, den = 0.f;
  for (int e = s0 + grp; e < s1; e += 4) {
    int   sv = srcP[e];          // uniform across the 16-lane group (broadcast)
    float wv = edgew(asrc[sv] + ad);
    den += wv;
    ushort2 u = *(const ushort2*)(h2b + (size_t)sv * OUTD + cl * 2);
    a0 += wv * b2f(u.x);
    a1 += wv * b2f(u.y);
  }
  // reduce the 4 edge-groups (lane xor 16, 32)
  a0 += __shfl_xor(a0, 16); a0 += __shfl_xor(a0, 32);
  a1 += __shfl_xor(a1, 16); a1 += __shfl_xor(a1, 32);
  den += __shfl_xor(den, 16); den += __shfl_xor(den, 32);
  if (grp == 0) {
    float inv = 1.f / (den + 1e-16f);
    ushort2 o; o.x = f2b(a0 * inv); o.y = f2b(a1 * inv);
    *(ushort2*)(g2pad + (size_t)node * 64 + cl * 2) = o;
  } else if (grp == 1) {
    *(ushort2*)(g2pad + (size_t)node * 64 + 32 + cl * 2) = make_ushort2(0, 0);  // K-pad
  }
}

extern "C" void kernel_launch(void* const* d_in, const int* in_sizes, int n_in,
                              void* d_out, int out_size, void* d_ws, size_t ws_size,
                              hipStream_t stream)
{
  const void*         feat = d_in[0];
  const unsigned int* eidx = (const unsigned int*)d_in[1];
  const void*         W1   = d_in[2];
  const void*         W2   = d_in[3];
  const void*         aS   = d_in[4];
  const void*         aD   = d_in[5];

  const int N = in_sizes[0] / INDIM;
  const int E = in_sizes[1] / 2;
  const int M_pad = ((N + 127) / 128) * 128;
  const int nb = (N + 1023) / 1024;

  char* w = (char*)d_ws;
  auto alloc = [&](size_t bytes) -> char* {
    char* p = w; w += (bytes + 255) & ~(size_t)255; return p;
  };
  unsigned short* featb = (unsigned short*)alloc((size_t)M_pad * INDIM * 2); // bf16 features
  unsigned short* H     = featb;   // ALIAS: h1/h3 [M_pad][256] — featb dead after xp1
  unsigned short* P     = (unsigned short*)alloc((size_t)M_pad * HIDD * 2);  // xp1
  unsigned short* h2b   = (unsigned short*)alloc((size_t)N * OUTD * 2);      // h2 bf16
  unsigned short* g2pad = (unsigned short*)alloc((size_t)M_pad * 64 * 2);    // agg(h2), K-padded
  float* asrc = (float*)alloc((size_t)N * 4);
  float* adst = (float*)alloc((size_t)N * 4);
  int*   srcP = (int*)alloc((size_t)E * 4);     // CSR-ordered edge src (the ONLY CSR payload)
  int*   deg  = (int*)alloc((size_t)N * 4);
  int*   offs = (int*)alloc((size_t)(N + 1) * 4);
  int*   cur  = (int*)alloc((size_t)N * 4);
  int*   bsum = (int*)alloc((size_t)(nb + 1) * 4);
  unsigned short* W1b   = (unsigned short*)alloc((size_t)INDIM * HIDD * 2); // [512][256]
  unsigned short* W1tb  = (unsigned short*)alloc((size_t)INDIM * HIDD * 2); // [256][512]
  unsigned short* W2b64 = (unsigned short*)alloc((size_t)HIDD * 64 * 2);    // [256][64]
  float* W2f  = (float*)alloc((size_t)HIDD * OUTD * 4);
  float* atS  = (float*)alloc((size_t)HIDD * 4);
  float* atD  = (float*)alloc((size_t)HIDD * 4);
  int*   flags = (int*)alloc(64);

  hipMemsetAsync(deg, 0, (size_t)N * 4, stream);

  probe_kernel<<<1, 256, 0, stream>>>((const unsigned int*)feat, eidx, flags);

  const int eb = (E + 255) / 256;
  deg_kernel<<<eb, 256, 0, stream>>>(eidx, deg, E, flags);
  prep_weights<<<512, 256, 0, stream>>>(W1, W2, aS, aD, W1b, W1tb, W2f, W2b64, atS, atD, flags);

  // features -> bf16
  convb_kernel<<<2048, 256, 0, stream>>>(feat, featb, (size_t)N * INDIM / 4, flags);

  const int mb = (N + 127) / 128;

  // xp1 = featb @ W1 : Bt = W1tb [256][512]
  gemm_nt2<0, 0><<<dim3(HIDD / 128, mb), 256, 0, stream>>>(
      featb, W1tb, P, nullptr, 0, flags, N, HIDD, INDIM);

  rowdots<<<(N + 3) / 4, 256, 0, stream>>>(P, atS, atD, asrc, adst, N);

  // CSR offsets (P3 also initializes cur = offs)
  scan_p1<<<nb, 256, 0, stream>>>(deg, bsum, N);
  scan_p2<<<1, 256, 0, stream>>>(bsum, nb);
  scan_p3<<<nb, 256, 0, stream>>>(deg, bsum, offs, cur, N, nb);

  // CSR fill: src indices only
  fill_kernel<<<eb, 256, 0, stream>>>(eidx, cur, srcP, E, flags);

  // GAT layer 1: h1 = elu(agg(xp1)/denom)   (H aliases featb — featb dead now)
  agg_elu2<<<(N + 3) / 4, 256, 0, stream>>>(P, asrc, adst, srcP, offs, H, N);

  // h2 = h1 @ W2 -> output 0 (+ bf16 copy for layer-2 agg)
  gemm_h2<<<(N + 7) / 8, 256, 0, stream>>>(H, W2f, d_out, h2b, flags, N);

  // GAT layer 2, commuted: g2 = agg(h2) [N,32->64pad]
  agg_small<<<(N + 3) / 4, 256, 0, stream>>>(h2b, asrc, adst, srcP, offs, g2pad, N);

  // h3 = elu(g2 @ W2^T) via MFMA GEMM: A = g2pad [M,64], Bt = W2b64 [256][64]
  gemm_nt2<0, 1><<<dim3(HIDD / 128, mb), 256, 0, stream>>>(
      g2pad, W2b64, H, nullptr, 0, flags, N, HIDD, 64);

  // h4 = h3 @ W1^T : Bt = W1b [512][256] -> output 1 (adaptive)
  gemm_nt2<1, 0><<<dim3(INDIM / 128, mb), 256, 0, stream>>>(
      H, W1b, nullptr, d_out, (size_t)N * OUTD, flags, N, INDIM, HIDD);
}